// Round 1
// baseline (75.561 us; speedup 1.0000x reference)
//
#include <hip/hip_runtime.h>
#include <math.h>

// CARAFE: features [2,64,64,128] f32, masks [2,128,128,25] f32 -> out [2,128,128,128] f32
// K=5, k2=25, groups G = 25/25 = 1, Cg = 128.
// Nearest upsample 64->128 half-pixel: src = dst >> 1.
// Patch j = di*5+dj reads features[b, r+di-2, c+dj-2, :], zero-padded OOB.

#define K  5
#define K2 25

__global__ __launch_bounds__(256) void carafe_kernel(
    const float* __restrict__ feat,   // [B,64,64,128]
    const float* __restrict__ masks,  // [B,128,128,25]
    float* __restrict__ out)          // [B,128,128,128]
{
    const int group = threadIdx.x >> 5;     // pixel slot within block, 0..7
    const int lane  = threadIdx.x & 31;     // 0..31: float4 channel slot

    const int pix = blockIdx.x * 8 + group; // 0 .. 32767  (B*H*W)
    const int b   = pix >> 14;              // / (128*128)
    const int rem = pix & 16383;
    const int Ho  = rem >> 7;
    const int Wo  = rem & 127;
    const int r   = Ho >> 1;                // low-res row
    const int c   = Wo >> 1;                // low-res col

    // ---- softmax over 25 mask logits, once per pixel (lanes 0..24 hold values)
    float mv = -INFINITY;
    if (lane < K2) mv = masks[pix * K2 + lane];
    float mx = mv;
    #pragma unroll
    for (int off = 16; off >= 1; off >>= 1)
        mx = fmaxf(mx, __shfl_xor(mx, off, 32));
    float e = (lane < K2) ? __expf(mv - mx) : 0.0f;
    float s = e;
    #pragma unroll
    for (int off = 16; off >= 1; off >>= 1)
        s += __shfl_xor(s, off, 32);
    const float wgt = e / s;

    // ---- weighted patch accumulation, 4 channels per lane (float4)
    float4 acc = make_float4(0.f, 0.f, 0.f, 0.f);
    const float4* featv = (const float4*)feat;   // 32 float4 per pixel (128 ch)

    #pragma unroll
    for (int j = 0; j < K2; ++j) {
        const int di = j / K;
        const int dj = j % K;
        const int rr = r + di - 2;
        const int cc = c + dj - 2;
        const float wj = __shfl(wgt, j, 32);     // broadcast weight j within pixel group
        if ((unsigned)rr < 64u && (unsigned)cc < 64u) {
            const float4 f = featv[(size_t)((b * 64 + rr) * 64 + cc) * 32 + lane];
            acc.x += f.x * wj;
            acc.y += f.y * wj;
            acc.z += f.z * wj;
            acc.w += f.w * wj;
        }
    }

    ((float4*)out)[(size_t)pix * 32 + lane] = acc;
}

extern "C" void kernel_launch(void* const* d_in, const int* in_sizes, int n_in,
                              void* d_out, int out_size, void* d_ws, size_t ws_size,
                              hipStream_t stream) {
    const float* feat  = (const float*)d_in[0];   // 2*64*64*128
    const float* masks = (const float*)d_in[1];   // 2*128*128*25
    float* out = (float*)d_out;                   // 2*128*128*128

    const int n_pix = 2 * 128 * 128;              // 32768
    dim3 grid(n_pix / 8), block(256);
    carafe_kernel<<<grid, block, 0, stream>>>(feat, masks, out);
}

// Round 2
// 71.835 us; speedup vs baseline: 1.0519x; 1.0519x over previous
//
#include <hip/hip_runtime.h>
#include <math.h>

// CARAFE: features [2,64,64,128] f32, masks [2,128,128,25] f32 -> out [2,128,128,128] f32
// K=5, k2=25, G=1, Cg=128. Nearest upsample 64->128 half-pixel: src = dst>>1,
// so each 2x2 output quad (2r..2r+1, 2c..2c+1) shares the same low-res pixel (r,c)
// and therefore the same 25 feature patch vectors — only the mask weights differ.
// One 32-lane group = one quad: load each feature float4 once, FMA into 4 accumulators.

#define K  5
#define K2 25

__global__ __launch_bounds__(256) void carafe_quad_kernel(
    const float* __restrict__ feat,   // [B,64,64,128]
    const float* __restrict__ masks,  // [B,128,128,25]
    float* __restrict__ out)          // [B,128,128,128]
{
    const int group = threadIdx.x >> 5;     // quad slot within block, 0..7
    const int lane  = threadIdx.x & 31;     // float4 channel slot (4 ch/lane)

    const int q   = blockIdx.x * 8 + group; // 0..16383  (B*64*64 quads)
    const int b   = q >> 12;                // / (64*64)
    const int rem = q & 4095;
    const int r   = rem >> 6;               // low-res row  (= Ho>>1)
    const int c   = rem & 63;               // low-res col  (= Wo>>1)

    // base output pixel index of the quad's top-left: (b, 2r, 2c)
    const int pix00 = ((b * 128 + 2 * r) * 128 + 2 * c);
    const int pixofs[4] = {0, 1, 128, 129};

    // ---- 4 softmaxes over 25 mask logits (lanes 0..24 hold values)
    float w[4];
    #pragma unroll
    for (int p = 0; p < 4; ++p) {
        const int pix = pix00 + pixofs[p];
        float mv = (lane < K2) ? masks[(size_t)pix * K2 + lane] : -INFINITY;
        float mx = mv;
        #pragma unroll
        for (int off = 16; off >= 1; off >>= 1)
            mx = fmaxf(mx, __shfl_xor(mx, off, 32));
        float e = (lane < K2) ? __expf(mv - mx) : 0.0f;
        float s = e;
        #pragma unroll
        for (int off = 16; off >= 1; off >>= 1)
            s += __shfl_xor(s, off, 32);
        w[p] = e / s;
    }

    // ---- weighted patch accumulation: each feature float4 loaded ONCE, used 4x
    float4 acc0 = make_float4(0.f, 0.f, 0.f, 0.f);
    float4 acc1 = acc0, acc2 = acc0, acc3 = acc0;

    const float4* featv = (const float4*)feat;          // 32 float4 per low-res pixel
    const size_t fbase = (size_t)b * 64 * 64 * 32;

    #pragma unroll
    for (int j = 0; j < K2; ++j) {
        const int di = j / K;
        const int dj = j % K;
        const int rr = r + di - 2;
        const int cc = c + dj - 2;
        // broadcast weights while all 32 lanes of the group are active
        const float w0 = __shfl(w[0], j, 32);
        const float w1 = __shfl(w[1], j, 32);
        const float w2 = __shfl(w[2], j, 32);
        const float w3 = __shfl(w[3], j, 32);
        if ((unsigned)rr < 64u && (unsigned)cc < 64u) {
            const float4 f = featv[fbase + ((size_t)(rr * 64 + cc)) * 32 + lane];
            acc0.x += f.x * w0; acc0.y += f.y * w0; acc0.z += f.z * w0; acc0.w += f.w * w0;
            acc1.x += f.x * w1; acc1.y += f.y * w1; acc1.z += f.z * w1; acc1.w += f.w * w1;
            acc2.x += f.x * w2; acc2.y += f.y * w2; acc2.z += f.z * w2; acc2.w += f.w * w2;
            acc3.x += f.x * w3; acc3.y += f.y * w3; acc3.z += f.z * w3; acc3.w += f.w * w3;
        }
    }

    // ---- write the 4 output pixels (each 512 B coalesced per group)
    float4* outv = (float4*)out;
    outv[(size_t)(pix00 +   0) * 32 + lane] = acc0;
    outv[(size_t)(pix00 +   1) * 32 + lane] = acc1;
    outv[(size_t)(pix00 + 128) * 32 + lane] = acc2;
    outv[(size_t)(pix00 + 129) * 32 + lane] = acc3;
}

extern "C" void kernel_launch(void* const* d_in, const int* in_sizes, int n_in,
                              void* d_out, int out_size, void* d_ws, size_t ws_size,
                              hipStream_t stream) {
    const float* feat  = (const float*)d_in[0];   // 2*64*64*128
    const float* masks = (const float*)d_in[1];   // 2*128*128*25
    float* out = (float*)d_out;                   // 2*128*128*128

    const int n_quads = 2 * 64 * 64;              // 8192 quads... per batch 4096; total 8192? -> 2*4096 = 8192
    // NOTE: quads = B * 64 * 64 = 2 * 4096 = 8192; 8 quads per block
    dim3 grid((2 * 64 * 64) / 8), block(256);
    carafe_quad_kernel<<<grid, block, 0, stream>>>(feat, masks, out);
    (void)n_quads;
}

// Round 3
// 71.140 us; speedup vs baseline: 1.0621x; 1.0098x over previous
//
#include <hip/hip_runtime.h>
#include <math.h>

// CARAFE: features [2,64,64,128] f32, masks [2,128,128,25] f32 -> out [2,128,128,128] f32
// K=5, k2=25, G=1, Cg=128. Nearest upsample 64->128 half-pixel: src = dst>>1,
// so each 2x2 output quad shares the same low-res pixel (r,c) and its 25 feature
// patch vectors — only the mask softmax weights differ.
// One 32-lane group = one quad. Weights staged in LDS as [j][4] so the j-loop does
// ONE broadcast ds_read_b128 per j instead of 4 shuffles. Accumulation in
// ext_vector float4 to let LLVM emit packed v_pk_fma_f32.

#define K  5
#define K2 25

typedef float v4f __attribute__((ext_vector_type(4)));

__global__ __launch_bounds__(256) void carafe_quad_kernel(
    const float* __restrict__ feat,   // [B,64,64,128]
    const float* __restrict__ masks,  // [B,128,128,25]
    float* __restrict__ out)          // [B,128,128,128]
{
    __shared__ v4f wq[8][K2];               // [quad slot][j] -> weights of the 4 quad pixels

    const int group = threadIdx.x >> 5;     // quad slot within block, 0..7
    const int lane  = threadIdx.x & 31;     // float4 channel slot (4 ch/lane)

    const int q   = blockIdx.x * 8 + group; // 0..8191  (B*64*64 quads)
    const int b   = q >> 12;                // / (64*64)
    const int rem = q & 4095;
    const int r   = rem >> 6;               // low-res row (= Ho>>1)
    const int c   = rem & 63;               // low-res col (= Wo>>1)

    const int pix00 = ((b * 128 + 2 * r) * 128 + 2 * c);
    const int pixofs[4] = {0, 1, 128, 129};

    // ---- 4 softmaxes over 25 mask logits (lane j holds logit j for j<25)
    float w[4];
    #pragma unroll
    for (int p = 0; p < 4; ++p) {
        const int pix = pix00 + pixofs[p];
        float mv = (lane < K2) ? masks[(size_t)pix * K2 + lane] : -INFINITY;
        float mx = mv;
        #pragma unroll
        for (int off = 16; off >= 1; off >>= 1)
            mx = fmaxf(mx, __shfl_xor(mx, off, 32));
        float e = (lane < K2) ? __expf(mv - mx) : 0.0f;
        float s = e;
        #pragma unroll
        for (int off = 16; off >= 1; off >>= 1)
            s += __shfl_xor(s, off, 32);
        w[p] = e / s;
    }
    if (lane < K2) {
        float* dst = (float*)&wq[group][lane];
        dst[0] = w[0]; dst[1] = w[1]; dst[2] = w[2]; dst[3] = w[3];
    }
    __syncthreads();   // cheap; removes any LDS write->read ordering doubt

    // ---- weighted patch accumulation: feature float4 loaded once, used for 4 pixels
    v4f acc0 = 0.f, acc1 = 0.f, acc2 = 0.f, acc3 = 0.f;
    const v4f* featv = (const v4f*)feat;            // 32 float4 per low-res pixel
    const size_t fbase = (size_t)b * (64 * 64 * 32);

    #pragma unroll
    for (int j = 0; j < K2; ++j) {
        const int di = j / K;
        const int dj = j % K;
        const int rr = r + di - 2;
        const int cc = c + dj - 2;
        if ((unsigned)rr < 64u && (unsigned)cc < 64u) {
            const v4f wj = wq[group][j];            // ds_read_b128, broadcast (conflict-free)
            const v4f f  = featv[fbase + (size_t)(rr * 64 + cc) * 32 + lane];
            acc0 += f * wj.x;
            acc1 += f * wj.y;
            acc2 += f * wj.z;
            acc3 += f * wj.w;
        }
    }

    // ---- write the 4 output pixels (512 B coalesced per group)
    v4f* outv = (v4f*)out;
    outv[(size_t)(pix00 +   0) * 32 + lane] = acc0;
    outv[(size_t)(pix00 +   1) * 32 + lane] = acc1;
    outv[(size_t)(pix00 + 128) * 32 + lane] = acc2;
    outv[(size_t)(pix00 + 129) * 32 + lane] = acc3;
}

extern "C" void kernel_launch(void* const* d_in, const int* in_sizes, int n_in,
                              void* d_out, int out_size, void* d_ws, size_t ws_size,
                              hipStream_t stream) {
    const float* feat  = (const float*)d_in[0];   // 2*64*64*128
    const float* masks = (const float*)d_in[1];   // 2*128*128*25
    float* out = (float*)d_out;                   // 2*128*128*128

    // quads = B * 64 * 64 = 8192; 8 quads (256 threads) per block
    dim3 grid((2 * 64 * 64) / 8), block(256);
    carafe_quad_kernel<<<grid, block, 0, stream>>>(feat, masks, out);
}